// Round 1
// baseline (16100.157 us; speedup 1.0000x reference)
//
#include <hip/hip_runtime.h>
#include <cstdint>
#include <cstddef>

typedef unsigned short u16;
typedef unsigned int u32;
typedef __attribute__((ext_vector_type(8))) short short8;
typedef __attribute__((ext_vector_type(4))) float f32x4;

#define AGENT_SCOPE __HIP_MEMORY_SCOPE_AGENT
#define SPIN_CAP 20000000
#define SMEM_BYTES 154632

__device__ __forceinline__ u16 f2bf(float f) {
  u32 u = __float_as_uint(f);
  return (u16)((u + 0x7FFFu + ((u >> 16) & 1u)) >> 16);
}
__device__ __forceinline__ float bf2f(u16 s) { return __uint_as_float(((u32)s) << 16); }
__device__ __forceinline__ float sigm(float x) { return 1.f / (1.f + __expf(-x)); }
__device__ __forceinline__ float tanha(float x) { return 1.f - 2.f / (__expf(2.f * x) + 1.f); }

__device__ __forceinline__ uint4 pack8(const float* p) {
  uint4 v;
  v.x = (u32)f2bf(p[0]) | ((u32)f2bf(p[1]) << 16);
  v.y = (u32)f2bf(p[2]) | ((u32)f2bf(p[3]) << 16);
  v.z = (u32)f2bf(p[4]) | ((u32)f2bf(p[5]) << 16);
  v.w = (u32)f2bf(p[6]) | ((u32)f2bf(p[7]) << 16);
  return v;
}

// Persistent LSTM autoencoder kernel.
// Grid: 256 WGs x 256 thr. col = bid&3 (batch slice of 16), rowg = bid>>2
// (hidden slice of 8 units -> 32 gate rows). LDS ~151KB forces 1 WG/CU so
// all 256 blocks are co-resident -> flag barriers are safe.
__global__ void __launch_bounds__(256, 1)
lstm_ae_kernel(const float* __restrict__ x,
    const float* __restrict__ eWih0, const float* __restrict__ eWhh0,
    const float* __restrict__ ebi0,  const float* __restrict__ ebh0,
    const float* __restrict__ eWih1, const float* __restrict__ eWhh1,
    const float* __restrict__ ebi1,  const float* __restrict__ ebh1,
    const float* __restrict__ dWhh0,
    const float* __restrict__ dbi0,  const float* __restrict__ dbh0,
    const float* __restrict__ dWih1, const float* __restrict__ dWhh1,
    const float* __restrict__ dbi1,  const float* __restrict__ dbh1,
    const float* __restrict__ tlW,   const float* __restrict__ tlb,
    const float* __restrict__ lhW,   const float* __restrict__ lhb,
    const float* __restrict__ opW,   const float* __restrict__ opb,
    float* __restrict__ out, char* __restrict__ wsb)
{
  extern __shared__ char smem[];
  u16* sW0   = (u16*)(smem);              // enc: [32][648] cat(Wih0|Whh0); dec: [32][520] Whh0, opW slice @ u16 ofs 16640
  u16* sW1   = (u16*)(smem + 41472);      // [32][1032] cat(Wih1|Whh1)
  u16* sX    = (u16*)(smem + 107520);     // [16][136] x_t slice (bf16)
  u16* sH0   = (u16*)(smem + 111872);     // [16][520] staged h0 (bf16)
  u16* sH1   = (u16*)(smem + 128512);     // [16][520] staged h1 (bf16)
  float* sP  = (float*)(smem + 145152);   // [2][2][2][16][16] MFMA partials / recon scratch
  float* sBias = (float*)(smem + 153344); // [2][32]
  float* sC  = (float*)(smem + 153600);   // [2][16][8] cell state (fp32)
  float* sOPB= (float*)(smem + 154624);   // [2]

  #define SP(li,nt,pt,mm,nn) sP[((((li)*2+(nt))*2+(pt))*16+(mm))*16+(nn)]

  u32* flags = (u32*)wsb;                 // [4][64] flag lines, 64B apart
  u32* gcnt  = (u32*)(wsb + 16384);       // global barrier counter
  float* zbuf= (float*)(wsb + 16448);     // [64][64] latent z
  u16* h0r   = (u16*)(wsb + 32832);       // [2][4][16][512] bf16 ring
  u16* h1r   = (u16*)(wsb + 163904);      // [2][4][16][512] bf16 ring
  u32* h0ru  = (u32*)h0r;
  u32* h1ru  = (u32*)h1r;
  u32* outu  = (u32*)out;

  const int tid  = threadIdx.x;
  const int col  = blockIdx.x & 3;
  const int rowg = blockIdx.x >> 2;
  const int wid  = tid >> 6;
  const int lane = tid & 63;
  const int m    = lane & 15;            // A-row (batch) / B-row (gate) within tile
  const int qo   = (lane >> 4) * 8;      // k sub-offset of fragment

  u32 ep = 0;

  // ---- column barrier: per-WG flag lines; wave0 polls all 64 with one vector load;
  // one acquire load emits the L2 invalidate that makes later regular loads coherent.
  auto colbar = [&]() {
    ++ep;
    __syncthreads();   // drains all threads' global stores (vmcnt0 before s_barrier)
    if (tid == 0)
      __hip_atomic_store(&flags[(col*64 + rowg)*16], ep, __ATOMIC_RELEASE, AGENT_SCOPE);
    if (tid < 64) {
      u32* f = &flags[(col*64 + tid)*16];
      int it = 0;
      while (__hip_atomic_load(f, __ATOMIC_RELAXED, AGENT_SCOPE) < ep && ++it < SPIN_CAP) {}
      (void)__hip_atomic_load(f, __ATOMIC_ACQUIRE, AGENT_SCOPE);
    }
    __syncthreads();
  };

  // stage one [16][512] bf16 ring matrix into LDS (row stride 520 for bank-safety)
  auto stage_ring = [&](u16* dst, const u16* src) {
    int b = tid >> 4, seg = tid & 15;
    const uint4* s4 = (const uint4*)(src + b*512 + seg*32);
    uint4 v0 = s4[0], v1 = s4[1], v2 = s4[2], v3 = s4[3];
    uint4* d4 = (uint4*)(dst + b*520 + seg*32);
    d4[0]=v0; d4[1]=v1; d4[2]=v2; d4[3]=v3;
  };

  auto stage_xt = [&](int s) {
    int b = tid >> 4, seg = tid & 15;
    const float* p = x + (size_t)(col*16 + b)*131072 + (size_t)s*128 + seg*8;
    uint4 v;
    v.x = (u32)f2bf(p[0]) | ((u32)f2bf(p[1]) << 16);
    v.y = (u32)f2bf(p[2]) | ((u32)f2bf(p[3]) << 16);
    v.z = (u32)f2bf(p[4]) | ((u32)f2bf(p[5]) << 16);
    v.w = (u32)f2bf(p[6]) | ((u32)f2bf(p[7]) << 16);
    *(uint4*)(sX + b*136 + seg*8) = v;
  };

  // gate activations + state update + bf16 h write to ring (agent-scope, packed dwords)
  auto act_store = [&](bool L0a, bool L1a, int p0, int p1) {
    int li = tid >> 7, b = (tid >> 3) & 15, u = tid & 7;
    bool act = li ? L1a : L0a;
    float hv = 0.f;
    if (act) {
      float gi = SP(li,0,0,b,u)   + SP(li,0,1,b,u)   + sBias[li*32 + u];
      float gf = SP(li,0,0,b,8+u) + SP(li,0,1,b,8+u) + sBias[li*32 + 8 + u];
      float gg = SP(li,1,0,b,u)   + SP(li,1,1,b,u)   + sBias[li*32 + 16 + u];
      float go = SP(li,1,0,b,8+u) + SP(li,1,1,b,8+u) + sBias[li*32 + 24 + u];
      float c = sC[(li*16 + b)*8 + u];
      c = sigm(gf)*c + sigm(gi)*tanha(gg);
      sC[(li*16 + b)*8 + u] = c;
      hv = sigm(go)*tanha(c);
    }
    u16 hb = f2bf(hv);
    u32 other = __shfl_xor((u32)hb, 1);
    if (act && !(u & 1)) {
      u32 v = (u32)hb | (other << 16);
      u32* ring = li ? h1ru : h0ru;
      int par = li ? p1 : p0;
      int idx = ((par*4 + col)*16 + b)*256 + ((rowg*8 + u) >> 1);
      __hip_atomic_store(ring + idx, v, __ATOMIC_RELAXED, AGENT_SCOPE);
    }
  };

  // ================= P0: load encoder weights (fp32 -> bf16 LDS) =================
  for (int i = tid; i < 32*80; i += 256) {      // W0cat [32][640]
    int n = i / 80, k = (i % 80) * 8;
    int g = ((n >> 3) << 9) + rowg*8 + (n & 7);
    const float* src = (k < 128) ? (eWih0 + g*128 + k) : (eWhh0 + g*512 + (k - 128));
    *(uint4*)(sW0 + n*648 + k) = pack8(src);
  }
  for (int i = tid; i < 32*128; i += 256) {     // W1cat [32][1024]
    int n = i >> 7, k = (i & 127) * 8;
    int g = ((n >> 3) << 9) + rowg*8 + (n & 7);
    const float* src = (k < 512) ? (eWih1 + g*512 + k) : (eWhh1 + g*512 + (k - 512));
    *(uint4*)(sW1 + n*1032 + k) = pack8(src);
  }
  if (tid < 64) {
    int li = tid >> 5, n = tid & 31;
    int g = ((n >> 3) << 9) + rowg*8 + (n & 7);
    sBias[li*32 + n] = li ? (ebi1[g] + ebh1[g]) : (ebi0[g] + ebh0[g]);
  }
  sC[tid] = 0.f;
  __syncthreads();

  // ================= P1: encoder scan (layer1 lag-1 pipelined; 1 barrier/slot) ====
  for (int s = 0; s <= 1024; ++s) {
    const bool L0 = (s < 1024);
    const bool L1 = (s >= 1);
    if (L0) stage_xt(s);
    stage_ring(sH0, h0r + ((((s-1)&1)*4) + col) * 8192);   // h0[s-1]
    stage_ring(sH1, h1r + ((((s-2)&1)*4) + col) * 8192);   // h1[s-2]
    __syncthreads();

    f32x4 acc0 = {0.f,0.f,0.f,0.f}, acc1 = {0.f,0.f,0.f,0.f};
    auto run = [&](const u16* Wb, int wstr, const u16* Ab, int astr, int nkt, int bk0, int ak0) {
      for (int i2 = 0; i2 < nkt; ++i2) {
        short8 a  = *(const short8*)(Ab + m*astr + ak0 + i2*32 + qo);
        short8 b0 = *(const short8*)(Wb + m*wstr + bk0 + i2*32 + qo);
        short8 b1 = *(const short8*)(Wb + (16+m)*wstr + bk0 + i2*32 + qo);
        acc0 = __builtin_amdgcn_mfma_f32_16x16x32_bf16(a, b0, acc0, 0, 0, 0);
        acc1 = __builtin_amdgcn_mfma_f32_16x16x32_bf16(a, b1, acc1, 0, 0, 0);
      }
    };
    if      (wid == 0) { if (L0) { run(sW0,648, sX,136, 4, 0, 0); run(sW0,648, sH0,520, 6, 128, 0); } }
    else if (wid == 1) { if (L0) run(sW0,648, sH0,520, 10, 320, 192); }
    else if (wid == 2) { if (L1) run(sW1,1032, sH0,520, 16, 0, 0); }
    else               { if (L1) run(sW1,1032, sH1,520, 16, 512, 0); }
    {
      const bool wact = (wid < 2) ? L0 : L1;
      if (wact) {
        int li = wid >> 1, pt = wid & 1, mb = (lane >> 4) * 4;
        #pragma unroll
        for (int r = 0; r < 4; ++r) {
          SP(li,0,pt, mb+r, m) = acc0[r];
          SP(li,1,pt, mb+r, m) = acc1[r];
        }
      }
    }
    __syncthreads();
    act_store(L0, L1, s & 1, (s-1) & 1);
    colbar();
  }

  // ================= P2: latent heads =================
  stage_ring(sH1, h1r + (4 + col) * 8192);   // h1[1023] (parity 1)
  __syncthreads();
  if (tid < 16) {     // z[b, rowg] = h1_T[b,:] . tlW[rowg,:] + tlb[rowg]
    int b = tid;
    float acc = tlb[rowg];
    for (int kk = 0; kk < 512; kk += 8) {
      short8 hv = *(const short8*)(sH1 + b*520 + kk);
      #pragma unroll
      for (int j = 0; j < 8; ++j) acc += bf2f((u16)hv[j]) * tlW[rowg*512 + kk + j];
    }
    int gb = col*16 + b;
    __hip_atomic_store(outu + 8388608 + gb*64 + rowg, __float_as_uint(acc), __ATOMIC_RELAXED, AGENT_SCOPE);
    __hip_atomic_store((u32*)zbuf + gb*64 + rowg, __float_as_uint(acc), __ATOMIC_RELAXED, AGENT_SCOPE);
  }
  __syncthreads();
  if (tid == 0) {     // global barrier (init_h mixes z across batch columns)
    __hip_atomic_fetch_add(gcnt, 1u, __ATOMIC_RELEASE, AGENT_SCOPE);
    int it = 0;
    while (__hip_atomic_load(gcnt, __ATOMIC_RELAXED, AGENT_SCOPE) < 256u && ++it < SPIN_CAP) {}
    (void)__hip_atomic_load(gcnt, __ATOMIC_ACQUIRE, AGENT_SCOPE);
  }
  __syncthreads();

  // ---- decoder weights ----
  for (int i = tid; i < 32*64; i += 256) {      // W0dec [32][512] = Whh0_dec
    int n = i >> 6, k = (i & 63) * 8;
    int g = ((n >> 3) << 9) + rowg*8 + (n & 7);
    *(uint4*)(sW0 + n*520 + k) = pack8(dWhh0 + g*512 + k);
  }
  for (int i = tid; i < 32*128; i += 256) {     // W1cat dec
    int n = i >> 7, k = (i & 127) * 8;
    int g = ((n >> 3) << 9) + rowg*8 + (n & 7);
    const float* src = (k < 512) ? (dWih1 + g*512 + k) : (dWhh1 + g*512 + (k - 512));
    *(uint4*)(sW1 + n*1032 + k) = pack8(src);
  }
  for (int i = tid; i < 2*64; i += 256) {       // opW slice: rows rowg*2, rowg*2+1
    int dd = i >> 6, k = (i & 63) * 8;
    *(uint4*)(sW0 + 16640 + dd*520 + k) = pack8(opW + (rowg*2 + dd)*512 + k);
  }
  if (tid < 64) {
    int li = tid >> 5, n = tid & 31;
    int g = ((n >> 3) << 9) + rowg*8 + (n & 7);
    sBias[li*32 + n] = li ? (dbi1[g] + dbh1[g]) : (dbi0[g] + dbh0[g]);
  }
  if (tid < 2) sOPB[tid] = opb[rowg*2 + tid];
  sC[tid] = 0.f;
  // ---- init_h = tanh(z @ lhW^T + lhb) with torch-style flat reshape (L,B,H):
  // init_h[l][b][h] = M[l*32 + b/2][(b&1)*512 + h]
  {
    int li = tid >> 7, hh = (tid >> 4) & 7, qb = (tid >> 3) & 1, u = tid & 7;
    int r = li*32 + 8*col + hh;
    int c = qb*512 + rowg*8 + u;
    int bl = 2*hh + qb;
    float acc = lhb[c];
    for (int k = 0; k < 64; ++k) acc += zbuf[r*64 + k] * lhW[c*64 + k];
    u16 hb = f2bf(tanha(acc));
    u32 other = __shfl_xor((u32)hb, 1);
    if (!(u & 1)) {
      u32 v = (u32)hb | (other << 16);
      u32* ring = li ? h1ru : h0ru;
      int idx = ((4 + col)*16 + bl)*256 + ((rowg*8 + u) >> 1);   // parity 1 = "h[-1]"
      __hip_atomic_store(ring + idx, v, __ATOMIC_RELAXED, AGENT_SCOPE);
    }
  }
  colbar();

  // ================= P3: decoder scan + fused output projection ===========
  for (int s = 0; s <= 1025; ++s) {
    const bool L0 = (s < 1024);
    const bool L1 = (s >= 1 && s <= 1024);
    const bool RC = (s >= 2);
    stage_ring(sH0, h0r + ((((s-1)&1)*4) + col) * 8192);
    stage_ring(sH1, h1r + ((((s-2)&1)*4) + col) * 8192);
    __syncthreads();

    f32x4 acc0 = {0.f,0.f,0.f,0.f}, acc1 = {0.f,0.f,0.f,0.f};
    auto run = [&](const u16* Wb, int wstr, const u16* Ab, int astr, int nkt, int bk0, int ak0) {
      for (int i2 = 0; i2 < nkt; ++i2) {
        short8 a  = *(const short8*)(Ab + m*astr + ak0 + i2*32 + qo);
        short8 b0 = *(const short8*)(Wb + m*wstr + bk0 + i2*32 + qo);
        short8 b1 = *(const short8*)(Wb + (16+m)*wstr + bk0 + i2*32 + qo);
        acc0 = __builtin_amdgcn_mfma_f32_16x16x32_bf16(a, b0, acc0, 0, 0, 0);
        acc1 = __builtin_amdgcn_mfma_f32_16x16x32_bf16(a, b1, acc1, 0, 0, 0);
      }
    };
    if      (wid == 0) { if (L0) run(sW0,520, sH0,520, 8, 0, 0); }
    else if (wid == 1) { if (L0) run(sW0,520, sH0,520, 8, 256, 256); }
    else if (wid == 2) { if (L1) run(sW1,1032, sH0,520, 16, 0, 0); }
    else               { if (L1) run(sW1,1032, sH1,520, 16, 512, 0); }
    {
      const bool wact = (wid < 2) ? L0 : L1;
      if (wact) {
        int li = wid >> 1, pt = wid & 1, mb = (lane >> 4) * 4;
        #pragma unroll
        for (int r = 0; r < 4; ++r) {
          SP(li,0,pt, mb+r, m) = acc0[r];
          SP(li,1,pt, mb+r, m) = acc1[r];
        }
      }
    }
    __syncthreads();
    act_store(L0, L1, s & 1, (s-1) & 1);

    if (RC) {   // recon[tau = s-2] = sigmoid(h1dec[tau] @ opW^T + opb), d in {2*rowg, 2*rowg+1}
      __syncthreads();
      int b = tid >> 4, dd = (tid >> 3) & 1, pt = tid & 7;
      float acc = 0.f;
      int k0 = pt * 64;
      for (int kk = 0; kk < 64; kk += 8) {
        short8 hv = *(const short8*)(sH1 + b*520 + k0 + kk);
        short8 wv = *(const short8*)(sW0 + 16640 + dd*520 + k0 + kk);
        #pragma unroll
        for (int j = 0; j < 8; ++j) acc += bf2f((u16)hv[j]) * bf2f((u16)wv[j]);
      }
      sP[tid] = acc;
      __syncthreads();
      if (tid < 32) {
        int b2 = tid >> 1, d2 = tid & 1;
        float sum = sOPB[d2];
        #pragma unroll
        for (int j = 0; j < 8; ++j) sum += sP[b2*16 + d2*8 + j];
        float rv = sigm(sum);
        size_t oidx = (size_t)(col*16 + b2)*131072 + (size_t)(s - 2)*128 + rowg*2 + d2;
        __hip_atomic_store(outu + oidx, __float_as_uint(rv), __ATOMIC_RELAXED, AGENT_SCOPE);
      }
    }
    if (s < 1025) colbar();
  }
  #undef SP
}

extern "C" void kernel_launch(void* const* d_in, const int* in_sizes, int n_in,
                              void* d_out, int out_size, void* d_ws, size_t ws_size,
                              hipStream_t stream) {
  (void)in_sizes; (void)n_in; (void)out_size; (void)ws_size;
  hipFuncSetAttribute(reinterpret_cast<const void*>(lstm_ae_kernel),
                      hipFuncAttributeMaxDynamicSharedMemorySize, SMEM_BYTES);
  // zero flags / gcnt / rings (enc initial h = 0); re-done every launch (ws is re-poisoned)
  hipMemsetAsync(d_ws, 0, 294976, stream);
  lstm_ae_kernel<<<dim3(256), dim3(256), SMEM_BYTES, stream>>>(
      (const float*)d_in[0],
      (const float*)d_in[1],  (const float*)d_in[2],
      (const float*)d_in[3],  (const float*)d_in[4],
      (const float*)d_in[5],  (const float*)d_in[6],
      (const float*)d_in[7],  (const float*)d_in[8],
      (const float*)d_in[10],
      (const float*)d_in[11], (const float*)d_in[12],
      (const float*)d_in[13], (const float*)d_in[14],
      (const float*)d_in[15], (const float*)d_in[16],
      (const float*)d_in[17], (const float*)d_in[18],
      (const float*)d_in[19], (const float*)d_in[20],
      (const float*)d_in[21], (const float*)d_in[22],
      (float*)d_out, (char*)d_ws);
}